// Round 4
// baseline (469.637 us; speedup 1.0000x reference)
//
#include <hip/hip_runtime.h>
#include <hip/hip_bf16.h>

typedef __hip_bfloat16 bf16;
typedef __attribute__((ext_vector_type(8))) short short8;
typedef __attribute__((ext_vector_type(4))) float f32x4;

#define S_LEN 4096
#define HID_DIM 2048

// 1/sqrt(128) * log2(e): folded into Q so softmax runs in exp2 domain
#define QSCALE ((float)(0.08838834764831845 * 1.4426950408889634))

__device__ __forceinline__ void gld_lds16(const void* g, void* l) {
  __builtin_amdgcn_global_load_lds(
      (const __attribute__((address_space(1))) void*)g,
      (__attribute__((address_space(3))) void*)l, 16, 0, 0);
}

// ---------------- fp32 -> bf16 convert ----------------
__global__ __launch_bounds__(256) void k_cvt(const float* __restrict__ src,
                                             bf16* __restrict__ dst, int n) {
  long i = ((long)blockIdx.x * 256 + threadIdx.x) * 8;
  if (i >= n) return;
  float4 a = *reinterpret_cast<const float4*>(src + i);
  float4 b = *reinterpret_cast<const float4*>(src + i + 4);
  float v[8] = {a.x, a.y, a.z, a.w, b.x, b.y, b.z, b.w};
  short8 o;
#pragma unroll
  for (int j = 0; j < 8; ++j) {
    bf16 h = __float2bfloat16(v[j]);
    o[j] = *reinterpret_cast<short*>(&h);
  }
  *reinterpret_cast<short8*>(dst + i) = o;
}

// ---------------- bf16 GEMM, C = A * B^T (A:[M,K], B:[N,K]) ----
template <typename OutT>
__global__ __launch_bounds__(256) void k_gemm_bt(
    const bf16* __restrict__ A, const bf16* __restrict__ B,
    OutT* __restrict__ C, int M, int N, int K) {
  __shared__ bf16 Al[2][128 * 32];
  __shared__ bf16 Bl[2][128 * 32];
  const int tid = threadIdx.x;
  const int lane = tid & 63;
  const int wid = tid >> 6;
  const int wr = wid >> 1;
  const int wc = wid & 1;
  const long brow = (long)blockIdx.y * 128;
  const long bcol = (long)blockIdx.x * 128;
  const int rsub = lane >> 2;
  const int ksub = (lane & 3) * 8;

  f32x4 acc[4][4];
#pragma unroll
  for (int i = 0; i < 4; ++i)
#pragma unroll
    for (int j = 0; j < 4; ++j) acc[i][j] = (f32x4){0.f, 0.f, 0.f, 0.f};

  const int NT = K >> 5;

  auto stage = [&](int buf, int kt) {
    const long k0 = (long)kt << 5;
#pragma unroll
    for (int ci = 0; ci < 2; ++ci) {
      const int c = wid + ci * 4;
      gld_lds16(A + (brow + c * 16 + rsub) * K + k0 + ksub, &Al[buf][c * 512]);
      gld_lds16(B + (bcol + c * 16 + rsub) * K + k0 + ksub, &Bl[buf][c * 512]);
    }
  };

  stage(0, 0);
  __syncthreads();

  const int arow = wr * 64 + (lane & 15);
  const int nrow = wc * 64 + (lane & 15);
  const int kk = (lane >> 4) * 8;

  for (int t = 0; t < NT; ++t) {
    const int buf = t & 1;
    if (t + 1 < NT) stage(buf ^ 1, t + 1);
    short8 af[4], bfr[4];
#pragma unroll
    for (int mt = 0; mt < 4; ++mt)
      af[mt] = *reinterpret_cast<const short8*>(&Al[buf][(arow + mt * 16) * 32 + kk]);
#pragma unroll
    for (int nt = 0; nt < 4; ++nt)
      bfr[nt] = *reinterpret_cast<const short8*>(&Bl[buf][(nrow + nt * 16) * 32 + kk]);
#pragma unroll
    for (int mt = 0; mt < 4; ++mt)
#pragma unroll
      for (int nt = 0; nt < 4; ++nt)
        acc[mt][nt] = __builtin_amdgcn_mfma_f32_16x16x32_bf16(af[mt], bfr[nt],
                                                              acc[mt][nt], 0, 0, 0);
    __syncthreads();
  }

#pragma unroll
  for (int mt = 0; mt < 4; ++mt) {
    const long r0 = brow + wr * 64 + mt * 16 + (lane >> 4) * 4;
#pragma unroll
    for (int nt = 0; nt < 4; ++nt) {
      const long c0 = bcol + wc * 64 + nt * 16 + (lane & 15);
#pragma unroll
      for (int r = 0; r < 4; ++r) {
        if constexpr (sizeof(OutT) == 2)
          C[(r0 + r) * N + c0] = __float2bfloat16(acc[mt][nt][r]);
        else
          C[(r0 + r) * N + c0] = acc[mt][nt][r];
      }
    }
  }
}

// ---------------- RMSNorm + RoPE + layout for attention ----------------
// QKVb bf16 [S][4096]; row idx: 0..15 q heads, 16..23 k heads, 24..31 v heads
__global__ __launch_bounds__(256) void k_normrope(
    const bf16* __restrict__ QKVb, const float* __restrict__ cosb,
    const float* __restrict__ sinb, const float* __restrict__ qw,
    const float* __restrict__ kw, bf16* __restrict__ Qb, bf16* __restrict__ Kb,
    bf16* __restrict__ Vb) {
  const int lane = threadIdx.x & 63;
  const int row = blockIdx.x * 4 + (threadIdx.x >> 6);
  const int s = row >> 5;
  const int idx = row & 31;
  const bf16* src = QKVb + (size_t)s * 4096 + idx * 128;
  float x0 = __bfloat162float(src[lane]);
  float x1 = __bfloat162float(src[lane + 64]);
  if (idx < 24) {
    float ss = x0 * x0 + x1 * x1;
#pragma unroll
    for (int off = 1; off < 64; off <<= 1) ss += __shfl_xor(ss, off);
    const float rn = rsqrtf(ss * (1.f / 128.f) + 1e-6f);
    const float* w = (idx < 16) ? qw : kw;
    x0 = x0 * rn * w[lane];
    x1 = x1 * rn * w[lane + 64];
    const float c0 = cosb[(size_t)s * 128 + lane];
    const float c1 = cosb[(size_t)s * 128 + lane + 64];
    const float s0 = sinb[(size_t)s * 128 + lane];
    const float s1 = sinb[(size_t)s * 128 + lane + 64];
    float o0 = x0 * c0 - x1 * s0;
    float o1 = x1 * c1 + x0 * s1;
    if (idx < 16) { o0 *= QSCALE; o1 *= QSCALE; }
    bf16* dst = (idx < 16) ? (Qb + ((size_t)idx * S_LEN + s) * 128)
                           : (Kb + ((size_t)(idx - 16) * S_LEN + s) * 128);
    dst[lane] = __float2bfloat16(o0);
    dst[lane + 64] = __float2bfloat16(o1);
  } else {
    bf16* dst = Vb + ((size_t)(idx - 24) * S_LEN + s) * 128;
    dst[lane] = __float2bfloat16(x0);
    dst[lane + 64] = __float2bfloat16(x1);
  }
}

// ---------------- V transpose: Vb [KV][S][128] -> Vt [KV][128][S] ----------
__global__ __launch_bounds__(256) void k_vt(const bf16* __restrict__ Vb,
                                            bf16* __restrict__ Vt) {
  __shared__ bf16 Lds[64][136];
  const int tid = threadIdx.x;
  const int s0 = blockIdx.x * 64;
  const int kv = blockIdx.y;
#pragma unroll
  for (int pass = 0; pass < 4; ++pass) {
    const int c = tid + pass * 256;
    const int r = c >> 4;
    const int off = (c & 15) * 8;
    *reinterpret_cast<short8*>(&Lds[r][off]) =
        *reinterpret_cast<const short8*>(
            &Vb[((size_t)kv * S_LEN + s0 + r) * 128 + off]);
  }
  __syncthreads();
#pragma unroll
  for (int pass = 0; pass < 4; ++pass) {
    const int c = tid + pass * 256;
    const int d = c >> 3;
    const int so = (c & 7) * 8;
    short8 o;
#pragma unroll
    for (int j = 0; j < 8; ++j) {
      bf16 e = Lds[so + j][d];
      o[j] = *reinterpret_cast<short*>(&e);
    }
    *reinterpret_cast<short8*>(&Vt[((size_t)kv * 128 + d) * S_LEN + s0 + so]) = o;
  }
}

// ---------------- causal flash attention (GQA 16q/8kv, D=128) ----------------
// grid: (32, H); block handles q-tiles {bx, 63-bx}; reg-staged double buffer
__global__ __launch_bounds__(256) void k_attn(const bf16* __restrict__ Qb,
                                              const bf16* __restrict__ Kb,
                                              const bf16* __restrict__ Vt_g,
                                              bf16* __restrict__ AO) {
  __shared__ bf16 Kl[64][136];   // K tile [kv][d], padded
  __shared__ bf16 Vl[128][72];   // V^T tile [d][kv], padded
  __shared__ bf16 Pl[4][16 * 72];
  const int tid = threadIdx.x;
  const int lane = tid & 63;
  const int wv = tid >> 6;
  const int h = blockIdx.y;
  const int kvh = h >> 1;
  const int c16 = lane & 15;
  const int kk = (lane >> 4) * 8;

  const bf16* Kbase = Kb + (size_t)kvh * S_LEN * 128;
  const bf16* Vbase = Vt_g + (size_t)kvh * 128 * S_LEN;

  short8 kreg[4], vreg[4];
  auto ld_regs = [&](int t) {
#pragma unroll
    for (int c = 0; c < 4; ++c) {
      const int ch = tid + c * 256;
      kreg[c] = *reinterpret_cast<const short8*>(
          &Kbase[((size_t)(t * 64 + (ch >> 4))) * 128 + (ch & 15) * 8]);
      vreg[c] = *reinterpret_cast<const short8*>(
          &Vbase[((size_t)(ch >> 3)) * S_LEN + t * 64 + (ch & 7) * 8]);
    }
  };
  auto st_lds = [&]() {
#pragma unroll
    for (int c = 0; c < 4; ++c) {
      const int ch = tid + c * 256;
      *reinterpret_cast<short8*>(&Kl[ch >> 4][(ch & 15) * 8]) = kreg[c];
      *reinterpret_cast<short8*>(&Vl[ch >> 3][(ch & 7) * 8]) = vreg[c];
    }
  };

  for (int half = 0; half < 2; ++half) {
    const int qt = half ? (63 - blockIdx.x) : blockIdx.x;
    const int qrow = qt * 64 + wv * 16;

    short8 qf[4];
    {
      const bf16* qp = Qb + ((size_t)h * S_LEN + qrow + c16) * 128 + kk;
#pragma unroll
      for (int ks = 0; ks < 4; ++ks)
        qf[ks] = *reinterpret_cast<const short8*>(qp + ks * 32);
    }

    f32x4 oacc[8];
#pragma unroll
    for (int i = 0; i < 8; ++i) oacc[i] = (f32x4){0.f, 0.f, 0.f, 0.f};
    float m_run[4] = {-1e30f, -1e30f, -1e30f, -1e30f};
    float l_run[4] = {0.f, 0.f, 0.f, 0.f};

    auto tile = [&](int t, bool mask) {
      // S = Q K^T (exp2 domain; Q pre-scaled)
      f32x4 sacc[4];
#pragma unroll
      for (int nt = 0; nt < 4; ++nt) sacc[nt] = (f32x4){0.f, 0.f, 0.f, 0.f};
      __builtin_amdgcn_s_setprio(1);
#pragma unroll
      for (int ks = 0; ks < 4; ++ks) {
#pragma unroll
        for (int nt = 0; nt < 4; ++nt) {
          short8 kf =
              *reinterpret_cast<const short8*>(&Kl[nt * 16 + c16][ks * 32 + kk]);
          sacc[nt] = __builtin_amdgcn_mfma_f32_16x16x32_bf16(qf[ks], kf,
                                                             sacc[nt], 0, 0, 0);
        }
      }
      __builtin_amdgcn_s_setprio(0);

      // online softmax (defer-rescale, exp2)
#pragma unroll
      for (int r = 0; r < 4; ++r) {
        const int grow = qrow + (lane >> 4) * 4 + r;
        float tm = -1e30f;
#pragma unroll
        for (int nt = 0; nt < 4; ++nt) {
          float sv = sacc[nt][r];
          if (mask && (t * 64 + nt * 16 + c16 > grow)) sv = -1e30f;
          sacc[nt][r] = sv;
          tm = fmaxf(tm, sv);
        }
#pragma unroll
        for (int off = 1; off < 16; off <<= 1)
          tm = fmaxf(tm, __shfl_xor(tm, off));
        if (__any(tm > m_run[r] + 8.f)) {
          const float mn = fmaxf(m_run[r], tm);
          const float alpha = exp2f(m_run[r] - mn);
          m_run[r] = mn;
          l_run[r] *= alpha;
#pragma unroll
          for (int dn = 0; dn < 8; ++dn) oacc[dn][r] *= alpha;
        }
        float rs = 0.f;
#pragma unroll
        for (int nt = 0; nt < 4; ++nt) {
          const float p = exp2f(sacc[nt][r] - m_run[r]);
          sacc[nt][r] = p;
          rs += p;
        }
#pragma unroll
        for (int off = 1; off < 16; off <<= 1) rs += __shfl_xor(rs, off);
        l_run[r] += rs;
      }

      // P -> LDS (wave-private)
#pragma unroll
      for (int r = 0; r < 4; ++r)
#pragma unroll
        for (int nt = 0; nt < 4; ++nt)
          Pl[wv][((lane >> 4) * 4 + r) * 72 + nt * 16 + c16] =
              __float2bfloat16(sacc[nt][r]);

      // O += P V
      __builtin_amdgcn_s_setprio(1);
#pragma unroll
      for (int ks = 0; ks < 2; ++ks) {
        short8 pf =
            *reinterpret_cast<const short8*>(&Pl[wv][c16 * 72 + ks * 32 + kk]);
#pragma unroll
        for (int dn = 0; dn < 8; ++dn) {
          short8 vf =
              *reinterpret_cast<const short8*>(&Vl[dn * 16 + c16][ks * 32 + kk]);
          oacc[dn] =
              __builtin_amdgcn_mfma_f32_16x16x32_bf16(pf, vf, oacc[dn], 0, 0, 0);
        }
      }
      __builtin_amdgcn_s_setprio(0);
    };

    // prologue: stage tile 0
    ld_regs(0);
    __syncthreads();  // protect prior half's LDS readers
    st_lds();
    __syncthreads();

    for (int t = 0; t < qt; ++t) {
      ld_regs(t + 1);          // issue next tile's loads (hidden under compute)
      tile(t, false);          // interior tiles: no causal mask
      __syncthreads();
      st_lds();
      __syncthreads();
    }
    tile(qt, true);            // diagonal tile

    // epilogue: O /= l
#pragma unroll
    for (int r = 0; r < 4; ++r) {
      const float inv = 1.f / l_run[r];
      const size_t row = (size_t)(qrow + (lane >> 4) * 4 + r);
#pragma unroll
      for (int dn = 0; dn < 8; ++dn)
        AO[row * HID_DIM + h * 128 + dn * 16 + c16] =
            __float2bfloat16(oacc[dn][r] * inv);
    }
  }
}

extern "C" void kernel_launch(void* const* d_in, const int* in_sizes, int n_in,
                              void* d_out, int out_size, void* d_ws,
                              size_t ws_size, hipStream_t stream) {
  (void)in_sizes; (void)n_in; (void)out_size; (void)ws_size;
  const float* hs = (const float*)d_in[0];
  const float* cosb = (const float*)d_in[1];
  const float* sinb = (const float*)d_in[2];
  const float* wq = (const float*)d_in[3];
  const float* wk = (const float*)d_in[4];
  const float* wv = (const float*)d_in[5];
  const float* wo = (const float*)d_in[6];
  const float* qnw = (const float*)d_in[7];
  const float* knw = (const float*)d_in[8];
  float* out = (float*)d_out;
  char* ws = (char*)d_ws;

  // workspace layout (bytes)
  bf16* Ah = (bf16*)(ws + 0);              // hidden bf16        16.78 MB
  bf16* Wqkv = (bf16*)(ws + 16777216);     // packed qkv weights 16.78 MB
  bf16* Wo = (bf16*)(ws + 33554432);       // wo bf16             8.39 MB
  bf16* QKVb = (bf16*)(ws + 41943040);     // qkv proj bf16      33.55 MB
  bf16* Qb = (bf16*)(ws + 75497472);       // Q [H][S][D]        16.78 MB
  bf16* Kb = (bf16*)(ws + 92274688);       // K [KV][S][D]        8.39 MB
  bf16* Vb = (bf16*)(ws + 100663296);      // V [KV][S][D]        8.39 MB
  bf16* AO = (bf16*)(ws + 109051904);      // attn out [S][H*D]  16.78 MB
  bf16* Vt = (bf16*)(ws + 125829120);      // V^T [KV][128][S]    8.39 MB

  auto cvt = [&](const float* s, bf16* d, long n) {
    k_cvt<<<dim3((unsigned)((n / 8 + 255) / 256)), dim3(256), 0, stream>>>(
        s, d, (int)n);
  };
  cvt(hs, Ah, (long)S_LEN * HID_DIM);
  cvt(wq, Wqkv, (long)2048 * 2048);
  cvt(wk, Wqkv + (long)2048 * 2048, (long)1024 * 2048);
  cvt(wv, Wqkv + (long)3072 * 2048, (long)1024 * 2048);
  cvt(wo, Wo, (long)2048 * 2048);

  k_gemm_bt<bf16><<<dim3(32, 32), dim3(256), 0, stream>>>(Ah, Wqkv, QKVb, 4096,
                                                          4096, 2048);
  k_normrope<<<dim3(32768), dim3(256), 0, stream>>>(QKVb, cosb, sinb, qnw, knw,
                                                    Qb, Kb, Vb);
  k_vt<<<dim3(64, 8), dim3(256), 0, stream>>>(Vb, Vt);
  k_attn<<<dim3(32, 16), dim3(256), 0, stream>>>(Qb, Kb, Vt, AO);
  k_gemm_bt<float><<<dim3(16, 32), dim3(256), 0, stream>>>(AO, Wo, out, 4096,
                                                           2048, 2048);
}

// Round 5
// 342.715 us; speedup vs baseline: 1.3703x; 1.3703x over previous
//
#include <hip/hip_runtime.h>
#include <hip/hip_bf16.h>

typedef __hip_bfloat16 bf16;
typedef __attribute__((ext_vector_type(8))) short short8;
typedef __attribute__((ext_vector_type(4))) float f32x4;

#define S_LEN 4096
#define HID_DIM 2048

// 1/sqrt(128) * log2(e): folded into Q so softmax runs in exp2 domain
#define QSCALE ((float)(0.08838834764831845 * 1.4426950408889634))

__device__ __forceinline__ void gld_lds16(const void* g, void* l) {
  __builtin_amdgcn_global_load_lds(
      (const __attribute__((address_space(1))) void*)g,
      (__attribute__((address_space(3))) void*)l, 16, 0, 0);
}

__device__ __forceinline__ float fexp2(float x) {
  return __builtin_amdgcn_exp2f(x);  // bare v_exp_f32
}

// DPP-based reduction across each 16-lane row (VALU latency, no DS ops)
template <int CTRL>
__device__ __forceinline__ float dppf(float x) {
  return __builtin_bit_cast(
      float, __builtin_amdgcn_update_dpp(0, __builtin_bit_cast(int, x), CTRL,
                                         0xf, 0xf, true));
}
__device__ __forceinline__ float rmax16(float x) {
  x = fmaxf(x, dppf<0xB1>(x));   // quad_perm [1,0,3,2]  (xor 1)
  x = fmaxf(x, dppf<0x4E>(x));   // quad_perm [2,3,0,1]  (xor 2)
  x = fmaxf(x, dppf<0x141>(x));  // row_half_mirror      (xor-4 class)
  x = fmaxf(x, dppf<0x140>(x));  // row_mirror           (xor-8 class)
  return x;
}
__device__ __forceinline__ float rsum16(float x) {
  x += dppf<0xB1>(x);
  x += dppf<0x4E>(x);
  x += dppf<0x141>(x);
  x += dppf<0x140>(x);
  return x;
}

// ---------------- fp32 -> bf16 convert ----------------
__global__ __launch_bounds__(256) void k_cvt(const float* __restrict__ src,
                                             bf16* __restrict__ dst, int n) {
  long i = ((long)blockIdx.x * 256 + threadIdx.x) * 8;
  if (i >= n) return;
  float4 a = *reinterpret_cast<const float4*>(src + i);
  float4 b = *reinterpret_cast<const float4*>(src + i + 4);
  float v[8] = {a.x, a.y, a.z, a.w, b.x, b.y, b.z, b.w};
  short8 o;
#pragma unroll
  for (int j = 0; j < 8; ++j) {
    bf16 h = __float2bfloat16(v[j]);
    o[j] = *reinterpret_cast<short*>(&h);
  }
  *reinterpret_cast<short8*>(dst + i) = o;
}

// ---------------- bf16 GEMM, C = A * B^T (A:[M,K], B:[N,K]) ----
template <typename OutT>
__global__ __launch_bounds__(256) void k_gemm_bt(
    const bf16* __restrict__ A, const bf16* __restrict__ B,
    OutT* __restrict__ C, int M, int N, int K) {
  __shared__ bf16 Al[2][128 * 32];
  __shared__ bf16 Bl[2][128 * 32];
  const int tid = threadIdx.x;
  const int lane = tid & 63;
  const int wid = tid >> 6;
  const int wr = wid >> 1;
  const int wc = wid & 1;
  const long brow = (long)blockIdx.y * 128;
  const long bcol = (long)blockIdx.x * 128;
  const int rsub = lane >> 2;
  const int ksub = (lane & 3) * 8;

  f32x4 acc[4][4];
#pragma unroll
  for (int i = 0; i < 4; ++i)
#pragma unroll
    for (int j = 0; j < 4; ++j) acc[i][j] = (f32x4){0.f, 0.f, 0.f, 0.f};

  const int NT = K >> 5;

  auto stage = [&](int buf, int kt) {
    const long k0 = (long)kt << 5;
#pragma unroll
    for (int ci = 0; ci < 2; ++ci) {
      const int c = wid + ci * 4;
      gld_lds16(A + (brow + c * 16 + rsub) * K + k0 + ksub, &Al[buf][c * 512]);
      gld_lds16(B + (bcol + c * 16 + rsub) * K + k0 + ksub, &Bl[buf][c * 512]);
    }
  };

  stage(0, 0);
  __syncthreads();

  const int arow = wr * 64 + (lane & 15);
  const int nrow = wc * 64 + (lane & 15);
  const int kk = (lane >> 4) * 8;

  for (int t = 0; t < NT; ++t) {
    const int buf = t & 1;
    if (t + 1 < NT) stage(buf ^ 1, t + 1);
    short8 af[4], bfr[4];
#pragma unroll
    for (int mt = 0; mt < 4; ++mt)
      af[mt] = *reinterpret_cast<const short8*>(&Al[buf][(arow + mt * 16) * 32 + kk]);
#pragma unroll
    for (int nt = 0; nt < 4; ++nt)
      bfr[nt] = *reinterpret_cast<const short8*>(&Bl[buf][(nrow + nt * 16) * 32 + kk]);
#pragma unroll
    for (int mt = 0; mt < 4; ++mt)
#pragma unroll
      for (int nt = 0; nt < 4; ++nt)
        acc[mt][nt] = __builtin_amdgcn_mfma_f32_16x16x32_bf16(af[mt], bfr[nt],
                                                              acc[mt][nt], 0, 0, 0);
    __syncthreads();
  }

#pragma unroll
  for (int mt = 0; mt < 4; ++mt) {
    const long r0 = brow + wr * 64 + mt * 16 + (lane >> 4) * 4;
#pragma unroll
    for (int nt = 0; nt < 4; ++nt) {
      const long c0 = bcol + wc * 64 + nt * 16 + (lane & 15);
#pragma unroll
      for (int r = 0; r < 4; ++r) {
        if constexpr (sizeof(OutT) == 2)
          C[(r0 + r) * N + c0] = __float2bfloat16(acc[mt][nt][r]);
        else
          C[(r0 + r) * N + c0] = acc[mt][nt][r];
      }
    }
  }
}

// ---------------- RMSNorm + RoPE + layout for attention ----------------
// QKVb bf16 [S][4096]; row idx: 0..15 q heads, 16..23 k heads, 24..31 v heads
__global__ __launch_bounds__(256) void k_normrope(
    const bf16* __restrict__ QKVb, const float* __restrict__ cosb,
    const float* __restrict__ sinb, const float* __restrict__ qw,
    const float* __restrict__ kw, bf16* __restrict__ Qb, bf16* __restrict__ Kb,
    bf16* __restrict__ Vb) {
  const int lane = threadIdx.x & 63;
  const int row = blockIdx.x * 4 + (threadIdx.x >> 6);
  const int s = row >> 5;
  const int idx = row & 31;
  const bf16* src = QKVb + (size_t)s * 4096 + idx * 128;
  float x0 = __bfloat162float(src[lane]);
  float x1 = __bfloat162float(src[lane + 64]);
  if (idx < 24) {
    float ss = x0 * x0 + x1 * x1;
#pragma unroll
    for (int off = 1; off < 64; off <<= 1) ss += __shfl_xor(ss, off);
    const float rn = rsqrtf(ss * (1.f / 128.f) + 1e-6f);
    const float* w = (idx < 16) ? qw : kw;
    x0 = x0 * rn * w[lane];
    x1 = x1 * rn * w[lane + 64];
    const float c0 = cosb[(size_t)s * 128 + lane];
    const float c1 = cosb[(size_t)s * 128 + lane + 64];
    const float s0 = sinb[(size_t)s * 128 + lane];
    const float s1 = sinb[(size_t)s * 128 + lane + 64];
    float o0 = x0 * c0 - x1 * s0;
    float o1 = x1 * c1 + x0 * s1;
    if (idx < 16) { o0 *= QSCALE; o1 *= QSCALE; }
    bf16* dst = (idx < 16) ? (Qb + ((size_t)idx * S_LEN + s) * 128)
                           : (Kb + ((size_t)(idx - 16) * S_LEN + s) * 128);
    dst[lane] = __float2bfloat16(o0);
    dst[lane + 64] = __float2bfloat16(o1);
  } else {
    bf16* dst = Vb + ((size_t)(idx - 24) * S_LEN + s) * 128;
    dst[lane] = __float2bfloat16(x0);
    dst[lane + 64] = __float2bfloat16(x1);
  }
}

// ---------------- V transpose: Vb [KV][S][128] -> Vt [KV][128][S] ----------
__global__ __launch_bounds__(256) void k_vt(const bf16* __restrict__ Vb,
                                            bf16* __restrict__ Vt) {
  __shared__ bf16 Lds[64][136];
  const int tid = threadIdx.x;
  const int s0 = blockIdx.x * 64;
  const int kv = blockIdx.y;
#pragma unroll
  for (int pass = 0; pass < 4; ++pass) {
    const int c = tid + pass * 256;
    const int r = c >> 4;
    const int off = (c & 15) * 8;
    *reinterpret_cast<short8*>(&Lds[r][off]) =
        *reinterpret_cast<const short8*>(
            &Vb[((size_t)kv * S_LEN + s0 + r) * 128 + off]);
  }
  __syncthreads();
#pragma unroll
  for (int pass = 0; pass < 4; ++pass) {
    const int c = tid + pass * 256;
    const int d = c >> 3;
    const int so = (c & 7) * 8;
    short8 o;
#pragma unroll
    for (int j = 0; j < 8; ++j) {
      bf16 e = Lds[so + j][d];
      o[j] = *reinterpret_cast<short*>(&e);
    }
    *reinterpret_cast<short8*>(&Vt[((size_t)kv * 128 + d) * S_LEN + s0 + so]) = o;
  }
}

// ---------------- causal flash attention (GQA 16q/8kv, D=128) ----------------
// grid: (32, H); block handles q-tiles {bx, 63-bx} (balanced: 65 KV tiles)
__global__ __launch_bounds__(256) void k_attn(const bf16* __restrict__ Qb,
                                              const bf16* __restrict__ Kb,
                                              const bf16* __restrict__ Vt_g,
                                              bf16* __restrict__ AO) {
  __shared__ bf16 Kl[64][136];   // K tile [kv][d], padded
  __shared__ bf16 Vl[128][72];   // V^T tile [d][kv], padded
  __shared__ bf16 Pl[4][16 * 72];
  const int tid = threadIdx.x;
  const int lane = tid & 63;
  const int wv = tid >> 6;
  const int h = blockIdx.y;
  const int kvh = h >> 1;
  const int c16 = lane & 15;
  const int kk = (lane >> 4) * 8;

  const bf16* Kbase = Kb + (size_t)kvh * S_LEN * 128;
  const bf16* Vbase = Vt_g + (size_t)kvh * 128 * S_LEN;

  // direct global->LDS staging (R2 structure)
  auto stage = [&](int t) {
#pragma unroll
    for (int c = 0; c < 4; ++c) {
      const int ch = tid + c * 256;
      *reinterpret_cast<short8*>(&Kl[ch >> 4][(ch & 15) * 8]) =
          *reinterpret_cast<const short8*>(
              &Kbase[((size_t)(t * 64 + (ch >> 4))) * 128 + (ch & 15) * 8]);
      *reinterpret_cast<short8*>(&Vl[ch >> 3][(ch & 7) * 8]) =
          *reinterpret_cast<const short8*>(
              &Vbase[((size_t)(ch >> 3)) * S_LEN + t * 64 + (ch & 7) * 8]);
    }
  };

  for (int half = 0; half < 2; ++half) {
    const int qt = half ? (63 - blockIdx.x) : blockIdx.x;
    const int qrow = qt * 64 + wv * 16;

    short8 qf[4];
    {
      const bf16* qp = Qb + ((size_t)h * S_LEN + qrow + c16) * 128 + kk;
#pragma unroll
      for (int ks = 0; ks < 4; ++ks)
        qf[ks] = *reinterpret_cast<const short8*>(qp + ks * 32);
    }

    f32x4 oacc[8];
#pragma unroll
    for (int i = 0; i < 8; ++i) oacc[i] = (f32x4){0.f, 0.f, 0.f, 0.f};
    float m_run[4] = {-1e30f, -1e30f, -1e30f, -1e30f};
    float l_run[4] = {0.f, 0.f, 0.f, 0.f};

    auto tile = [&](int t, bool mask) {
      // S = Q K^T (exp2 domain; Q pre-scaled)
      f32x4 sacc[4];
#pragma unroll
      for (int nt = 0; nt < 4; ++nt) sacc[nt] = (f32x4){0.f, 0.f, 0.f, 0.f};
#pragma unroll
      for (int ks = 0; ks < 4; ++ks) {
#pragma unroll
        for (int nt = 0; nt < 4; ++nt) {
          short8 kf =
              *reinterpret_cast<const short8*>(&Kl[nt * 16 + c16][ks * 32 + kk]);
          sacc[nt] = __builtin_amdgcn_mfma_f32_16x16x32_bf16(qf[ks], kf,
                                                             sacc[nt], 0, 0, 0);
        }
      }

      // online softmax (defer-rescale, exp2, DPP reduces)
#pragma unroll
      for (int r = 0; r < 4; ++r) {
        const int grow = qrow + (lane >> 4) * 4 + r;
        float tm = -1e30f;
#pragma unroll
        for (int nt = 0; nt < 4; ++nt) {
          float sv = sacc[nt][r];
          if (mask && (t * 64 + nt * 16 + c16 > grow)) sv = -1e30f;
          sacc[nt][r] = sv;
          tm = fmaxf(tm, sv);
        }
        tm = rmax16(tm);
        if (__any(tm > m_run[r] + 8.f)) {
          const float mn = fmaxf(m_run[r], tm);
          const float alpha = fexp2(m_run[r] - mn);
          m_run[r] = mn;
          l_run[r] *= alpha;
#pragma unroll
          for (int dn = 0; dn < 8; ++dn) oacc[dn][r] *= alpha;
        }
        float rs = 0.f;
#pragma unroll
        for (int nt = 0; nt < 4; ++nt) {
          const float p = fexp2(sacc[nt][r] - m_run[r]);
          sacc[nt][r] = p;
          rs += p;
        }
        l_run[r] += rsum16(rs);
      }

      // P -> LDS (wave-private)
#pragma unroll
      for (int r = 0; r < 4; ++r)
#pragma unroll
        for (int nt = 0; nt < 4; ++nt)
          Pl[wv][((lane >> 4) * 4 + r) * 72 + nt * 16 + c16] =
              __float2bfloat16(sacc[nt][r]);

      // O += P V
#pragma unroll
      for (int ks = 0; ks < 2; ++ks) {
        short8 pf =
            *reinterpret_cast<const short8*>(&Pl[wv][c16 * 72 + ks * 32 + kk]);
#pragma unroll
        for (int dn = 0; dn < 8; ++dn) {
          short8 vf =
              *reinterpret_cast<const short8*>(&Vl[dn * 16 + c16][ks * 32 + kk]);
          oacc[dn] =
              __builtin_amdgcn_mfma_f32_16x16x32_bf16(pf, vf, oacc[dn], 0, 0, 0);
        }
      }
    };

    for (int t = 0; t < qt; ++t) {
      __syncthreads();
      stage(t);
      __syncthreads();
      tile(t, false);
    }
    __syncthreads();
    stage(qt);
    __syncthreads();
    tile(qt, true);

    // epilogue: O /= l
#pragma unroll
    for (int r = 0; r < 4; ++r) {
      const float inv = 1.f / l_run[r];
      const size_t row = (size_t)(qrow + (lane >> 4) * 4 + r);
#pragma unroll
      for (int dn = 0; dn < 8; ++dn)
        AO[row * HID_DIM + h * 128 + dn * 16 + c16] =
            __float2bfloat16(oacc[dn][r] * inv);
    }
  }
}

extern "C" void kernel_launch(void* const* d_in, const int* in_sizes, int n_in,
                              void* d_out, int out_size, void* d_ws,
                              size_t ws_size, hipStream_t stream) {
  (void)in_sizes; (void)n_in; (void)out_size; (void)ws_size;
  const float* hs = (const float*)d_in[0];
  const float* cosb = (const float*)d_in[1];
  const float* sinb = (const float*)d_in[2];
  const float* wq = (const float*)d_in[3];
  const float* wk = (const float*)d_in[4];
  const float* wv = (const float*)d_in[5];
  const float* wo = (const float*)d_in[6];
  const float* qnw = (const float*)d_in[7];
  const float* knw = (const float*)d_in[8];
  float* out = (float*)d_out;
  char* ws = (char*)d_ws;

  // workspace layout (bytes)
  bf16* Ah = (bf16*)(ws + 0);              // hidden bf16        16.78 MB
  bf16* Wqkv = (bf16*)(ws + 16777216);     // packed qkv weights 16.78 MB
  bf16* Wo = (bf16*)(ws + 33554432);       // wo bf16             8.39 MB
  bf16* QKVb = (bf16*)(ws + 41943040);     // qkv proj bf16      33.55 MB
  bf16* Qb = (bf16*)(ws + 75497472);       // Q [H][S][D]        16.78 MB
  bf16* Kb = (bf16*)(ws + 92274688);       // K [KV][S][D]        8.39 MB
  bf16* Vb = (bf16*)(ws + 100663296);      // V [KV][S][D]        8.39 MB
  bf16* AO = (bf16*)(ws + 109051904);      // attn out [S][H*D]  16.78 MB
  bf16* Vt = (bf16*)(ws + 125829120);      // V^T [KV][128][S]    8.39 MB

  auto cvt = [&](const float* s, bf16* d, long n) {
    k_cvt<<<dim3((unsigned)((n / 8 + 255) / 256)), dim3(256), 0, stream>>>(
        s, d, (int)n);
  };
  cvt(hs, Ah, (long)S_LEN * HID_DIM);
  cvt(wq, Wqkv, (long)2048 * 2048);
  cvt(wk, Wqkv + (long)2048 * 2048, (long)1024 * 2048);
  cvt(wv, Wqkv + (long)3072 * 2048, (long)1024 * 2048);
  cvt(wo, Wo, (long)2048 * 2048);

  k_gemm_bt<bf16><<<dim3(32, 32), dim3(256), 0, stream>>>(Ah, Wqkv, QKVb, 4096,
                                                          4096, 2048);
  k_normrope<<<dim3(32768), dim3(256), 0, stream>>>(QKVb, cosb, sinb, qnw, knw,
                                                    Qb, Kb, Vb);
  k_vt<<<dim3(64, 8), dim3(256), 0, stream>>>(Vb, Vt);
  k_attn<<<dim3(32, 16), dim3(256), 0, stream>>>(Qb, Kb, Vt, AO);
  k_gemm_bt<float><<<dim3(16, 32), dim3(256), 0, stream>>>(AO, Wo, out, 4096,
                                                           2048, 2048);
}

// Round 6
// 327.010 us; speedup vs baseline: 1.4362x; 1.0480x over previous
//
#include <hip/hip_runtime.h>
#include <hip/hip_bf16.h>

typedef __hip_bfloat16 bf16;
typedef __attribute__((ext_vector_type(8))) short short8;
typedef __attribute__((ext_vector_type(4))) float f32x4;

#define S_LEN 4096
#define HID_DIM 2048

// 1/sqrt(128) * log2(e): folded into Q so softmax runs in exp2 domain
#define QSCALE ((float)(0.08838834764831845 * 1.4426950408889634))

__device__ __forceinline__ void gld_lds16(const void* g, void* l) {
  __builtin_amdgcn_global_load_lds(
      (const __attribute__((address_space(1))) void*)g,
      (__attribute__((address_space(3))) void*)l, 16, 0, 0);
}

__device__ __forceinline__ float fexp2(float x) {
  return __builtin_amdgcn_exp2f(x);  // bare v_exp_f32
}

// DPP-based reduction across each 16-lane row (VALU latency, no DS ops)
template <int CTRL>
__device__ __forceinline__ float dppf(float x) {
  return __builtin_bit_cast(
      float, __builtin_amdgcn_update_dpp(0, __builtin_bit_cast(int, x), CTRL,
                                         0xf, 0xf, true));
}
__device__ __forceinline__ float rmax16(float x) {
  x = fmaxf(x, dppf<0xB1>(x));   // quad_perm xor1
  x = fmaxf(x, dppf<0x4E>(x));   // quad_perm xor2
  x = fmaxf(x, dppf<0x141>(x));  // row_half_mirror
  x = fmaxf(x, dppf<0x140>(x));  // row_mirror
  return x;
}
__device__ __forceinline__ float rsum16(float x) {
  x += dppf<0xB1>(x);
  x += dppf<0x4E>(x);
  x += dppf<0x141>(x);
  x += dppf<0x140>(x);
  return x;
}

// ---------------- fp32 -> bf16 convert ----------------
__global__ __launch_bounds__(256) void k_cvt(const float* __restrict__ src,
                                             bf16* __restrict__ dst, int n) {
  long i = ((long)blockIdx.x * 256 + threadIdx.x) * 8;
  if (i >= n) return;
  float4 a = *reinterpret_cast<const float4*>(src + i);
  float4 b = *reinterpret_cast<const float4*>(src + i + 4);
  float v[8] = {a.x, a.y, a.z, a.w, b.x, b.y, b.z, b.w};
  short8 o;
#pragma unroll
  for (int j = 0; j < 8; ++j) {
    bf16 h = __float2bfloat16(v[j]);
    o[j] = *reinterpret_cast<short*>(&h);
  }
  *reinterpret_cast<short8*>(dst + i) = o;
}

// ---------------- bf16 GEMM, C = A * B^T (A:[M,K], B:[N,K]) ----
template <typename OutT>
__global__ __launch_bounds__(256) void k_gemm_bt(
    const bf16* __restrict__ A, const bf16* __restrict__ B,
    OutT* __restrict__ C, int M, int N, int K) {
  __shared__ bf16 Al[2][128 * 32];
  __shared__ bf16 Bl[2][128 * 32];
  const int tid = threadIdx.x;
  const int lane = tid & 63;
  const int wid = tid >> 6;
  const int wr = wid >> 1;
  const int wc = wid & 1;
  const long brow = (long)blockIdx.y * 128;
  const long bcol = (long)blockIdx.x * 128;
  const int rsub = lane >> 2;
  const int ksub = (lane & 3) * 8;

  f32x4 acc[4][4];
#pragma unroll
  for (int i = 0; i < 4; ++i)
#pragma unroll
    for (int j = 0; j < 4; ++j) acc[i][j] = (f32x4){0.f, 0.f, 0.f, 0.f};

  const int NT = K >> 5;

  auto stage = [&](int buf, int kt) {
    const long k0 = (long)kt << 5;
#pragma unroll
    for (int ci = 0; ci < 2; ++ci) {
      const int c = wid + ci * 4;
      gld_lds16(A + (brow + c * 16 + rsub) * K + k0 + ksub, &Al[buf][c * 512]);
      gld_lds16(B + (bcol + c * 16 + rsub) * K + k0 + ksub, &Bl[buf][c * 512]);
    }
  };

  stage(0, 0);
  __syncthreads();

  const int arow = wr * 64 + (lane & 15);
  const int nrow = wc * 64 + (lane & 15);
  const int kk = (lane >> 4) * 8;

  for (int t = 0; t < NT; ++t) {
    const int buf = t & 1;
    if (t + 1 < NT) stage(buf ^ 1, t + 1);
    short8 af[4], bfr[4];
#pragma unroll
    for (int mt = 0; mt < 4; ++mt)
      af[mt] = *reinterpret_cast<const short8*>(&Al[buf][(arow + mt * 16) * 32 + kk]);
#pragma unroll
    for (int nt = 0; nt < 4; ++nt)
      bfr[nt] = *reinterpret_cast<const short8*>(&Bl[buf][(nrow + nt * 16) * 32 + kk]);
#pragma unroll
    for (int mt = 0; mt < 4; ++mt)
#pragma unroll
      for (int nt = 0; nt < 4; ++nt)
        acc[mt][nt] = __builtin_amdgcn_mfma_f32_16x16x32_bf16(af[mt], bfr[nt],
                                                              acc[mt][nt], 0, 0, 0);
    __syncthreads();
  }

#pragma unroll
  for (int mt = 0; mt < 4; ++mt) {
    const long r0 = brow + wr * 64 + mt * 16 + (lane >> 4) * 4;
#pragma unroll
    for (int nt = 0; nt < 4; ++nt) {
      const long c0 = bcol + wc * 64 + nt * 16 + (lane & 15);
#pragma unroll
      for (int r = 0; r < 4; ++r) {
        if constexpr (sizeof(OutT) == 2)
          C[(r0 + r) * N + c0] = __float2bfloat16(acc[mt][nt][r]);
        else
          C[(r0 + r) * N + c0] = acc[mt][nt][r];
      }
    }
  }
}

// ---------------- RMSNorm + RoPE + layout for attention ----------------
// QKVb bf16 [S][4096]; row idx: 0..15 q heads, 16..23 k heads, 24..31 v heads
__global__ __launch_bounds__(256) void k_normrope(
    const bf16* __restrict__ QKVb, const float* __restrict__ cosb,
    const float* __restrict__ sinb, const float* __restrict__ qw,
    const float* __restrict__ kw, bf16* __restrict__ Qb, bf16* __restrict__ Kb,
    bf16* __restrict__ Vb) {
  const int lane = threadIdx.x & 63;
  const int row = blockIdx.x * 4 + (threadIdx.x >> 6);
  const int s = row >> 5;
  const int idx = row & 31;
  const bf16* src = QKVb + (size_t)s * 4096 + idx * 128;
  float x0 = __bfloat162float(src[lane]);
  float x1 = __bfloat162float(src[lane + 64]);
  if (idx < 24) {
    float ss = x0 * x0 + x1 * x1;
#pragma unroll
    for (int off = 1; off < 64; off <<= 1) ss += __shfl_xor(ss, off);
    const float rn = rsqrtf(ss * (1.f / 128.f) + 1e-6f);
    const float* w = (idx < 16) ? qw : kw;
    x0 = x0 * rn * w[lane];
    x1 = x1 * rn * w[lane + 64];
    const float c0 = cosb[(size_t)s * 128 + lane];
    const float c1 = cosb[(size_t)s * 128 + lane + 64];
    const float s0 = sinb[(size_t)s * 128 + lane];
    const float s1 = sinb[(size_t)s * 128 + lane + 64];
    float o0 = x0 * c0 - x1 * s0;
    float o1 = x1 * c1 + x0 * s1;
    if (idx < 16) { o0 *= QSCALE; o1 *= QSCALE; }
    bf16* dst = (idx < 16) ? (Qb + ((size_t)idx * S_LEN + s) * 128)
                           : (Kb + ((size_t)(idx - 16) * S_LEN + s) * 128);
    dst[lane] = __float2bfloat16(o0);
    dst[lane + 64] = __float2bfloat16(o1);
  } else {
    bf16* dst = Vb + ((size_t)(idx - 24) * S_LEN + s) * 128;
    dst[lane] = __float2bfloat16(x0);
    dst[lane + 64] = __float2bfloat16(x1);
  }
}

// ---------------- V transpose: Vb [KV][S][128] -> Vt [KV][128][S] ----------
__global__ __launch_bounds__(256) void k_vt(const bf16* __restrict__ Vb,
                                            bf16* __restrict__ Vt) {
  __shared__ bf16 Lds[64][136];
  const int tid = threadIdx.x;
  const int s0 = blockIdx.x * 64;
  const int kv = blockIdx.y;
#pragma unroll
  for (int pass = 0; pass < 4; ++pass) {
    const int c = tid + pass * 256;
    const int r = c >> 4;
    const int off = (c & 15) * 8;
    *reinterpret_cast<short8*>(&Lds[r][off]) =
        *reinterpret_cast<const short8*>(
            &Vb[((size_t)kv * S_LEN + s0 + r) * 128 + off]);
  }
  __syncthreads();
#pragma unroll
  for (int pass = 0; pass < 4; ++pass) {
    const int c = tid + pass * 256;
    const int d = c >> 3;
    const int so = (c & 7) * 8;
    short8 o;
#pragma unroll
    for (int j = 0; j < 8; ++j) {
      bf16 e = Lds[so + j][d];
      o[j] = *reinterpret_cast<short*>(&e);
    }
    *reinterpret_cast<short8*>(&Vt[((size_t)kv * 128 + d) * S_LEN + s0 + so]) = o;
  }
}

// ---------------- causal flash attention (GQA 16q/8kv, D=128) ----------------
// grid: (32, H); block handles q-tiles {bx, 63-bx} (balanced: 65 KV tiles).
// Double-buffered K/V staged via async global_load_lds; linear LDS with
// XOR-swizzled chunks (swizzle applied on global src AND lds read: rule 21).
__global__ __launch_bounds__(256) void k_attn(const bf16* __restrict__ Qb,
                                              const bf16* __restrict__ Kb,
                                              const bf16* __restrict__ Vt_g,
                                              bf16* __restrict__ AO) {
  __shared__ bf16 Kl[2][64 * 128];   // [kv][d], chunk-swizzled, linear
  __shared__ bf16 Vl[2][128 * 64];   // [d][kv], chunk-swizzled, linear
  __shared__ bf16 Pl[4][16 * 72];
  const int tid = threadIdx.x;
  const int lane = tid & 63;
  const int wv = tid >> 6;
  const int h = blockIdx.y;
  const int kvh = h >> 1;
  const int c16 = lane & 15;
  const int kk = (lane >> 4) * 8;

  const bf16* Kbase = Kb + (size_t)kvh * S_LEN * 128;
  const bf16* Vbase = Vt_g + (size_t)kvh * 128 * S_LEN;

  // async stage tile t into buffer buf (LDS linear dest, swizzled global src)
  auto stage = [&](int t, int buf) {
    const bf16* Kt = Kbase + (size_t)t * 64 * 128;
    const bf16* Vt = Vbase + t * 64;
#pragma unroll
    for (int p = 0; p < 4; ++p) {   // K: 1024 chunks of 16B
      const int ch = tid + p * 256;
      const int row = ch >> 4, cp = ch & 15;
      const int c = (cp & 8) | ((cp & 7) ^ (row & 7));
      gld_lds16(Kt + row * 128 + c * 8, &Kl[buf][(wv * 64 + p * 256) * 8]);
    }
#pragma unroll
    for (int p = 0; p < 4; ++p) {   // V: 1024 chunks of 16B
      const int ch = tid + p * 256;
      const int d = ch >> 3, cp = ch & 7;
      const int c = cp ^ (d & 7);
      gld_lds16(Vt + (size_t)d * S_LEN + c * 8, &Vl[buf][(wv * 64 + p * 256) * 8]);
    }
  };

  for (int half = 0; half < 2; ++half) {
    const int qt = half ? (63 - blockIdx.x) : blockIdx.x;
    const int qrow = qt * 64 + wv * 16;

    __syncthreads();           // prior half's readers done before overwrite
    stage(0, 0);

    short8 qf[4];
    {
      const bf16* qp = Qb + ((size_t)h * S_LEN + qrow + c16) * 128 + kk;
#pragma unroll
      for (int ks = 0; ks < 4; ++ks)
        qf[ks] = *reinterpret_cast<const short8*>(qp + ks * 32);
    }

    f32x4 oacc[8];
#pragma unroll
    for (int i = 0; i < 8; ++i) oacc[i] = (f32x4){0.f, 0.f, 0.f, 0.f};
    float m_run[4] = {-1e30f, -1e30f, -1e30f, -1e30f};
    float l_run[4] = {0.f, 0.f, 0.f, 0.f};

    auto tile = [&](int t, int buf, bool mask) {
      // S = Q K^T (exp2 domain; Q pre-scaled)
      f32x4 sacc[4];
#pragma unroll
      for (int nt = 0; nt < 4; ++nt) sacc[nt] = (f32x4){0.f, 0.f, 0.f, 0.f};
#pragma unroll
      for (int ks = 0; ks < 4; ++ks) {
#pragma unroll
        for (int nt = 0; nt < 4; ++nt) {
          const int row = nt * 16 + c16;
          const int ck = ks * 4 + (lane >> 4);
          const int ckp = (ck & 8) | ((ck & 7) ^ (row & 7));
          short8 kf =
              *reinterpret_cast<const short8*>(&Kl[buf][row * 128 + ckp * 8]);
          sacc[nt] = __builtin_amdgcn_mfma_f32_16x16x32_bf16(qf[ks], kf,
                                                             sacc[nt], 0, 0, 0);
        }
      }

      // online softmax (defer-rescale, exp2, DPP reduces)
#pragma unroll
      for (int r = 0; r < 4; ++r) {
        const int grow = qrow + (lane >> 4) * 4 + r;
        float tm = -1e30f;
#pragma unroll
        for (int nt = 0; nt < 4; ++nt) {
          float sv = sacc[nt][r];
          if (mask && (t * 64 + nt * 16 + c16 > grow)) sv = -1e30f;
          sacc[nt][r] = sv;
          tm = fmaxf(tm, sv);
        }
        tm = rmax16(tm);
        if (__any(tm > m_run[r] + 8.f)) {
          const float mn = fmaxf(m_run[r], tm);
          const float alpha = fexp2(m_run[r] - mn);
          m_run[r] = mn;
          l_run[r] *= alpha;
#pragma unroll
          for (int dn = 0; dn < 8; ++dn) oacc[dn][r] *= alpha;
        }
        float rs = 0.f;
#pragma unroll
        for (int nt = 0; nt < 4; ++nt) {
          const float p = fexp2(sacc[nt][r] - m_run[r]);
          sacc[nt][r] = p;
          rs += p;
        }
        l_run[r] += rsum16(rs);
      }

      // P -> LDS (wave-private)
#pragma unroll
      for (int r = 0; r < 4; ++r)
#pragma unroll
        for (int nt = 0; nt < 4; ++nt)
          Pl[wv][((lane >> 4) * 4 + r) * 72 + nt * 16 + c16] =
              __float2bfloat16(sacc[nt][r]);

      // O += P V
#pragma unroll
      for (int ks = 0; ks < 2; ++ks) {
        short8 pf =
            *reinterpret_cast<const short8*>(&Pl[wv][c16 * 72 + ks * 32 + kk]);
#pragma unroll
        for (int dn = 0; dn < 8; ++dn) {
          const int d = dn * 16 + c16;
          const int cv = ks * 4 + (lane >> 4);
          const int cvp = cv ^ (d & 7);
          short8 vf =
              *reinterpret_cast<const short8*>(&Vl[buf][d * 64 + cvp * 8]);
          oacc[dn] =
              __builtin_amdgcn_mfma_f32_16x16x32_bf16(pf, vf, oacc[dn], 0, 0, 0);
        }
      }
    };

    __syncthreads();  // tile 0 staged (implicit vmcnt drain before barrier)
    int cur = 0;
    for (int t = 0; t < qt; ++t) {
      stage(t + 1, cur ^ 1);   // async prefetch next tile into other buffer
      tile(t, cur, false);
      __syncthreads();         // drains this wave's vmcnt; all waves synced
      cur ^= 1;
    }
    tile(qt, cur, true);       // diagonal tile

    // epilogue: O /= l
#pragma unroll
    for (int r = 0; r < 4; ++r) {
      const float inv = 1.f / l_run[r];
      const size_t row = (size_t)(qrow + (lane >> 4) * 4 + r);
#pragma unroll
      for (int dn = 0; dn < 8; ++dn)
        AO[row * HID_DIM + h * 128 + dn * 16 + c16] =
            __float2bfloat16(oacc[dn][r] * inv);
    }
  }
}

extern "C" void kernel_launch(void* const* d_in, const int* in_sizes, int n_in,
                              void* d_out, int out_size, void* d_ws,
                              size_t ws_size, hipStream_t stream) {
  (void)in_sizes; (void)n_in; (void)out_size; (void)ws_size;
  const float* hs = (const float*)d_in[0];
  const float* cosb = (const float*)d_in[1];
  const float* sinb = (const float*)d_in[2];
  const float* wq = (const float*)d_in[3];
  const float* wk = (const float*)d_in[4];
  const float* wv = (const float*)d_in[5];
  const float* wo = (const float*)d_in[6];
  const float* qnw = (const float*)d_in[7];
  const float* knw = (const float*)d_in[8];
  float* out = (float*)d_out;
  char* ws = (char*)d_ws;

  // workspace layout (bytes)
  bf16* Ah = (bf16*)(ws + 0);              // hidden bf16        16.78 MB
  bf16* Wqkv = (bf16*)(ws + 16777216);     // packed qkv weights 16.78 MB
  bf16* Wo = (bf16*)(ws + 33554432);       // wo bf16             8.39 MB
  bf16* QKVb = (bf16*)(ws + 41943040);     // qkv proj bf16      33.55 MB
  bf16* Qb = (bf16*)(ws + 75497472);       // Q [H][S][D]        16.78 MB
  bf16* Kb = (bf16*)(ws + 92274688);       // K [KV][S][D]        8.39 MB
  bf16* Vb = (bf16*)(ws + 100663296);      // V [KV][S][D]        8.39 MB
  bf16* AO = (bf16*)(ws + 109051904);      // attn out [S][H*D]  16.78 MB
  bf16* Vt = (bf16*)(ws + 125829120);      // V^T [KV][128][S]    8.39 MB

  auto cvt = [&](const float* s, bf16* d, long n) {
    k_cvt<<<dim3((unsigned)((n / 8 + 255) / 256)), dim3(256), 0, stream>>>(
        s, d, (int)n);
  };
  cvt(hs, Ah, (long)S_LEN * HID_DIM);
  cvt(wq, Wqkv, (long)2048 * 2048);
  cvt(wk, Wqkv + (long)2048 * 2048, (long)1024 * 2048);
  cvt(wv, Wqkv + (long)3072 * 2048, (long)1024 * 2048);
  cvt(wo, Wo, (long)2048 * 2048);

  k_gemm_bt<bf16><<<dim3(32, 32), dim3(256), 0, stream>>>(Ah, Wqkv, QKVb, 4096,
                                                          4096, 2048);
  k_normrope<<<dim3(32768), dim3(256), 0, stream>>>(QKVb, cosb, sinb, qnw, knw,
                                                    Qb, Kb, Vb);
  k_vt<<<dim3(64, 8), dim3(256), 0, stream>>>(Vb, Vt);
  k_attn<<<dim3(32, 16), dim3(256), 0, stream>>>(Qb, Kb, Vt, AO);
  k_gemm_bt<float><<<dim3(16, 32), dim3(256), 0, stream>>>(AO, Wo, out, 4096,
                                                           2048, 2048);
}